// Round 1
// baseline (231.681 us; speedup 1.0000x reference)
//
#include <hip/hip_runtime.h>
#include <hip/hip_bf16.h>

// Problem: 8-layer MLP, B=131072 rows.
//   h = x[B,2]; 7x (Linear(no bias) + ReLU): W0[256,2], W1..W6[256,256];
//   out = sigmoid(h @ W7.T), W7[3,256].  All fp32 in/out.
// Strategy: fused persistent-tile kernel. Weights (1.58MB) are L2-resident.
//   - prep kernel packs W1..W6 to bf16 in MFMA B-fragment order (coalesced loads)
//   - main kernel: 64 rows/block, activations live in LDS as bf16, layers 1..6
//     via v_mfma_f32_16x16x32_bf16 (fp32 accum), layers 0 and 7 in fp32 VALU.

#define HID 256
#define BM 64          // rows per block
#define NBLK 2048      // 131072 / 64
#define HPITCH 264     // 256 + 8 pad (row stride 528B, 16B aligned, 2-way LDS max)

typedef __attribute__((ext_vector_type(8))) short bf16x8;
typedef __attribute__((ext_vector_type(8))) unsigned short u16x8;
typedef __attribute__((ext_vector_type(4))) float f32x4;

__device__ __forceinline__ unsigned short f2bf(float f) {
    union { float f; unsigned u; } v; v.f = f;
    unsigned r = v.u + 0x7fffu + ((v.u >> 16) & 1u);   // RNE (no NaN post-ReLU)
    return (unsigned short)(r >> 16);
}
__device__ __forceinline__ float bf2f(unsigned short s) {
    union { unsigned u; float f; } v; v.u = ((unsigned)s) << 16;
    return v.f;
}

struct WPtrs { const float* w[6]; };

// Pack W1..W6 (fp32 [256][256], row n = out-feature, col k = in-feature) into
// bf16 fragments: Wp[L][kk][nt][lane][j] = W_L[nt*16 + (lane&15)][kk*32 + 8*(lane>>4) + j]
// so the main kernel's B-frag load is one coalesced dwordx4 per lane.
__global__ void pack_w_kernel(WPtrs wp, unsigned short* __restrict__ Wp) {
    int tid = blockIdx.x * 256 + threadIdx.x;      // 0 .. 49151
    int L   = tid >> 13;                           // 6 layers x 8192 slots
    int rem = tid & 8191;
    int kk  = rem >> 10;                           // 0..7
    int nt  = (rem >> 6) & 15;                     // 0..15
    int l   = rem & 63;                            // lane slot
    int n   = nt * 16 + (l & 15);
    int k0  = kk * 32 + 8 * (l >> 4);
    const float* src = wp.w[L] + n * HID + k0;
    u16x8 v;
#pragma unroll
    for (int j = 0; j < 8; ++j) v[j] = f2bf(src[j]);
    *(u16x8*)(Wp + (long)L * 65536 + (long)((kk * 16 + nt) * 64 + l) * 8) = v;
}

__launch_bounds__(256, 4)
__global__ void mlp_fused_kernel(const float* __restrict__ x,
                                 const float* __restrict__ W0,
                                 const float* __restrict__ W7,
                                 const unsigned short* __restrict__ Wp,
                                 float* __restrict__ out) {
    __shared__ __align__(16) unsigned short Hs[BM][HPITCH];  // 33,792 B activations (bf16)
    __shared__ float xs[BM][2];                              // 512 B
    __shared__ float w7s[3 * HID];                           // 3 KB

    const int tid = threadIdx.x;
    const long r0 = (long)blockIdx.x * BM;

    // ---- stage x tile and W7 ----
    if (tid < 2 * BM) ((float*)xs)[tid] = x[r0 * 2 + tid];
    w7s[tid]       = W7[tid];
    w7s[tid + 256] = W7[tid + 256];
    w7s[tid + 512] = W7[tid + 512];
    const float w00 = W0[2 * tid];       // thread t owns output column n = t for layer 0
    const float w01 = W0[2 * tid + 1];
    __syncthreads();

    // ---- layer 0: [B,2] @ W0.T, ReLU, -> bf16 LDS ----
#pragma unroll 8
    for (int m = 0; m < BM; ++m) {
        float h = fmaf(xs[m][0], w00, xs[m][1] * w01);
        Hs[m][tid] = f2bf(fmaxf(0.f, h));
    }
    __syncthreads();

    // ---- layers 1..6: MFMA. wave w owns cols [64w, 64w+64), all 64 rows ----
    const int l  = tid & 63;
    const int w  = tid >> 6;
    const int lr = l & 15;       // frag row (A) / col (B,D)
    const int lg = l >> 4;       // frag k-group (A,B) / row-group (D)

    for (int L = 0; L < 6; ++L) {
        const unsigned short* wl = Wp + (long)L * 65536;
        f32x4 acc[4][4];
#pragma unroll
        for (int mt = 0; mt < 4; ++mt)
#pragma unroll
            for (int nt = 0; nt < 4; ++nt) acc[mt][nt] = (f32x4){0.f, 0.f, 0.f, 0.f};

#pragma unroll
        for (int kk = 0; kk < 8; ++kk) {
            bf16x8 b[4];
#pragma unroll
            for (int nt = 0; nt < 4; ++nt)
                b[nt] = *(const bf16x8*)(wl + (long)((kk * 16 + 4 * w + nt) * 64 + l) * 8);
            bf16x8 a[4];
#pragma unroll
            for (int mt = 0; mt < 4; ++mt)
                a[mt] = *(const bf16x8*)(&Hs[16 * mt + lr][kk * 32 + 8 * lg]);
#pragma unroll
            for (int mt = 0; mt < 4; ++mt)
#pragma unroll
                for (int nt = 0; nt < 4; ++nt)
                    acc[mt][nt] = __builtin_amdgcn_mfma_f32_16x16x32_bf16(
                        a[mt], b[nt], acc[mt][nt], 0, 0, 0);
        }
        __syncthreads();   // all reads of Hs done; safe to overwrite in place
#pragma unroll
        for (int mt = 0; mt < 4; ++mt)
#pragma unroll
            for (int nt = 0; nt < 4; ++nt)
#pragma unroll
                for (int j = 0; j < 4; ++j) {
                    // D layout: row = 4*lg + j, col = lr (within 16x16 tile)
                    Hs[16 * mt + 4 * lg + j][64 * w + 16 * nt + lr] =
                        f2bf(fmaxf(0.f, acc[mt][nt][j]));
                }
        __syncthreads();
    }

    // ---- layer 7: [64,256] @ W7.T (N=3), sigmoid ----
    const int m = tid >> 2;      // row 0..63
    const int q = tid & 3;       // k-quarter
    float a0 = 0.f, a1 = 0.f, a2 = 0.f;
#pragma unroll
    for (int kb = 0; kb < 64; kb += 8) {
        u16x8 hv = *(const u16x8*)(&Hs[m][q * 64 + kb]);
#pragma unroll
        for (int j = 0; j < 8; ++j) {
            float h = bf2f(hv[j]);
            int k = q * 64 + kb + j;
            a0 = fmaf(h, w7s[k], a0);
            a1 = fmaf(h, w7s[HID + k], a1);
            a2 = fmaf(h, w7s[2 * HID + k], a2);
        }
    }
    a0 += __shfl_xor(a0, 1); a0 += __shfl_xor(a0, 2);
    a1 += __shfl_xor(a1, 1); a1 += __shfl_xor(a1, 2);
    a2 += __shfl_xor(a2, 1); a2 += __shfl_xor(a2, 2);
    if (q == 0) {
        long o = (r0 + m) * 3;
        out[o + 0] = 1.f / (1.f + __expf(-a0));
        out[o + 1] = 1.f / (1.f + __expf(-a1));
        out[o + 2] = 1.f / (1.f + __expf(-a2));
    }
}

extern "C" void kernel_launch(void* const* d_in, const int* in_sizes, int n_in,
                              void* d_out, int out_size, void* d_ws, size_t ws_size,
                              hipStream_t stream) {
    const float* x  = (const float*)d_in[0];
    const float* W0 = (const float*)d_in[1];
    WPtrs wp;
    for (int i = 0; i < 6; ++i) wp.w[i] = (const float*)d_in[2 + i];
    const float* W7 = (const float*)d_in[8];
    float* out = (float*)d_out;
    unsigned short* Wp = (unsigned short*)d_ws;   // needs 786,432 B

    pack_w_kernel<<<192, 256, 0, stream>>>(wp, Wp);
    mlp_fused_kernel<<<NBLK, 256, 0, stream>>>(x, W0, W7, Wp, out);
}

// Round 3
// 158.337 us; speedup vs baseline: 1.4632x; 1.4632x over previous
//
#include <hip/hip_runtime.h>
#include <hip/hip_bf16.h>

// 8-layer MLP, B=131072. Fused: acts in LDS (bf16), layers 1..6 via MFMA.
// R2 changes vs R1:
//  - operand swap per tile: mfma(A=Wfrag, B=H^T frag) -> D has lane = one batch
//    row x 4 consecutive features -> epilogue = cvt_pk x2 + ds_write_b64 (was
//    64 scalar b16 stores + 3-op f2bf each). Same pack data, same Hs reads.
//  - register double-buffered weight prefetch (kk+1 during kk, cross-layer at
//    kk==7); per-wave-contiguous Wp stream.
//  - launch_bounds(256,3) so dbuf regs don't spill (acc=64 AGPR + ~64 VGPR).

#define HID 256
#define BM 64          // rows per block
#define NBLK 2048      // 131072 / 64
#define HPITCH 264     // 256 + 8 pad; 528B rows (16B aligned, 2-way LDS max on b128)

typedef __attribute__((ext_vector_type(8))) short bf16x8;
typedef __attribute__((ext_vector_type(8))) unsigned short u16x8;
typedef __attribute__((ext_vector_type(4))) unsigned short u16x4;
typedef __attribute__((ext_vector_type(4))) float f32x4;

__device__ __forceinline__ unsigned short f2bf_rn(float f) {
    union { float f; unsigned u; } v; v.f = f;
    return (unsigned short)((v.u + 0x8000u) >> 16);   // round-half-up, 2 ops
}
__device__ __forceinline__ float bf2f(unsigned short s) {
    union { unsigned u; float f; } v; v.u = ((unsigned)s) << 16;
    return v.f;
}
__device__ __forceinline__ unsigned cvt_pk_bf16(float lo, float hi) {
    unsigned r;
    asm("v_cvt_pk_bf16_f32 %0, %1, %2" : "=v"(r) : "v"(lo), "v"(hi));
    return r;
}

struct WPtrs { const float* w[6]; };

// A-frag pack (weights are the MFMA *A* operand now):
//   Wp[(((L*4+w)*8+kk)*4+ft)*64 + l][j] = W_L[64w+16ft+(l&15)][32kk+8(l>>4)+j]
// Per (wave,layer) the 32 frags are a contiguous 32KB stream (L1/L2 friendly).
__global__ void pack_w_kernel(WPtrs wp, unsigned short* __restrict__ Wp) {
    int tid = blockIdx.x * 256 + threadIdx.x;      // 0 .. 49151
    int L   = tid >> 13;                           // 6 layers x 8192 slots
    int rem = tid & 8191;
    int w   = rem >> 11;                           // 0..3
    int kk  = (rem >> 8) & 7;                      // 0..7
    int ft  = (rem >> 6) & 3;                      // 0..3
    int l   = rem & 63;
    int n   = 64 * w + 16 * ft + (l & 15);         // feature row
    int k0  = 32 * kk + 8 * (l >> 4);
    const float* src = wp.w[L] + n * HID + k0;
    u16x8 v;
#pragma unroll
    for (int j = 0; j < 8; ++j) {
        union { float f; unsigned u; } c; c.f = src[j];
        unsigned r = c.u + 0x7fffu + ((c.u >> 16) & 1u);  // RNE for weights
        v[j] = (unsigned short)(r >> 16);
    }
    *(u16x8*)(Wp + (size_t)tid * 8) = v;
}

__launch_bounds__(256, 3)
__global__ void mlp_fused_kernel(const float* __restrict__ x,
                                 const float* __restrict__ W0,
                                 const float* __restrict__ W7,
                                 const unsigned short* __restrict__ Wp,
                                 float* __restrict__ out) {
    __shared__ __align__(16) unsigned short Hs[BM][HPITCH];  // 33,792 B
    __shared__ float xs[BM][2];
    __shared__ float w7s[3 * HID];

    const int tid = threadIdx.x;
    const int l   = tid & 63;
    const int w   = tid >> 6;
    const int lr  = l & 15;
    const int lg  = l >> 4;
    const long r0 = (long)blockIdx.x * BM;

    // wave-contiguous weight stream base; [L][w][kk][ft][lane][8] shorts
    const unsigned short* wbase = Wp + ((size_t)w << 14) + (size_t)l * 8;

    // issue first weight frags immediately (land during layer-0 VALU work)
    bf16x8 wb[2][4];
#pragma unroll
    for (int ft = 0; ft < 4; ++ft)
        wb[0][ft] = *(const bf16x8*)(wbase + ft * 512);

    // ---- stage x tile and W7 ----
    if (tid < 2 * BM) ((float*)xs)[tid] = x[r0 * 2 + tid];
    w7s[tid]       = W7[tid];
    w7s[tid + 256] = W7[tid + 256];
    w7s[tid + 512] = W7[tid + 512];
    const float w00 = W0[2 * tid];
    const float w01 = W0[2 * tid + 1];
    __syncthreads();

    // ---- layer 0: [B,2] @ W0.T, ReLU -> bf16 LDS (thread t owns col t) ----
#pragma unroll 8
    for (int m = 0; m < BM; ++m) {
        float h = fmaf(xs[m][0], w00, xs[m][1] * w01);
        Hs[m][tid] = f2bf_rn(fmaxf(0.f, h));
    }
    __syncthreads();

    // ---- layers 1..6: wave w owns features [64w,64w+64), all 64 rows ----
#pragma unroll
    for (int L = 0; L < 6; ++L) {
        f32x4 acc[4][4];   // [ft][mt]
#pragma unroll
        for (int ft = 0; ft < 4; ++ft)
#pragma unroll
            for (int mt = 0; mt < 4; ++mt) acc[ft][mt] = (f32x4){0.f, 0.f, 0.f, 0.f};

#pragma unroll
        for (int kk = 0; kk < 8; ++kk) {
            const int cur = kk & 1, nxt = cur ^ 1;
            // prefetch next frag set (next kk, or next layer's kk=0)
            if (kk < 7) {
#pragma unroll
                for (int ft = 0; ft < 4; ++ft)
                    wb[nxt][ft] = *(const bf16x8*)(wbase + L * 65536 + (kk + 1) * 2048 + ft * 512);
            } else if (L < 5) {
#pragma unroll
                for (int ft = 0; ft < 4; ++ft)
                    wb[nxt][ft] = *(const bf16x8*)(wbase + (L + 1) * 65536 + ft * 512);
            }
            bf16x8 a[4];   // H^T frags: lane = batch col 16mt+lr, k = 32kk+8lg..+7
#pragma unroll
            for (int mt = 0; mt < 4; ++mt)
                a[mt] = *(const bf16x8*)(&Hs[16 * mt + lr][32 * kk + 8 * lg]);
#pragma unroll
            for (int ft = 0; ft < 4; ++ft)
#pragma unroll
                for (int mt = 0; mt < 4; ++mt)
                    acc[ft][mt] = __builtin_amdgcn_mfma_f32_16x16x32_bf16(
                        wb[cur][ft], a[mt], acc[ft][mt], 0, 0, 0);
        }
        __syncthreads();   // all Hs reads done; safe to overwrite in place
        // D: lane holds batch row 16mt+lr, features 64w+16ft+4lg+{0..3}
#pragma unroll
        for (int ft = 0; ft < 4; ++ft)
#pragma unroll
            for (int mt = 0; mt < 4; ++mt) {
                f32x4 v = acc[ft][mt];
                union { unsigned u[2]; u16x4 s; } pk;
                pk.u[0] = cvt_pk_bf16(fmaxf(0.f, v[0]), fmaxf(0.f, v[1]));
                pk.u[1] = cvt_pk_bf16(fmaxf(0.f, v[2]), fmaxf(0.f, v[3]));
                *(u16x4*)(&Hs[16 * mt + lr][64 * w + 16 * ft + 4 * lg]) = pk.s;
            }
        __syncthreads();
    }

    // ---- layer 7: [64,256] @ W7.T (N=3), sigmoid ----
    const int m = tid >> 2;
    const int q = tid & 3;
    float a0 = 0.f, a1 = 0.f, a2 = 0.f;
#pragma unroll
    for (int kb = 0; kb < 64; kb += 8) {
        u16x8 hv = *(const u16x8*)(&Hs[m][q * 64 + kb]);
#pragma unroll
        for (int j = 0; j < 8; ++j) {
            float h = bf2f(hv[j]);
            int k = q * 64 + kb + j;
            a0 = fmaf(h, w7s[k], a0);
            a1 = fmaf(h, w7s[HID + k], a1);
            a2 = fmaf(h, w7s[2 * HID + k], a2);
        }
    }
    a0 += __shfl_xor(a0, 1); a0 += __shfl_xor(a0, 2);
    a1 += __shfl_xor(a1, 1); a1 += __shfl_xor(a1, 2);
    a2 += __shfl_xor(a2, 1); a2 += __shfl_xor(a2, 2);
    if (q == 0) {
        long o = (r0 + m) * 3;
        out[o + 0] = 1.f / (1.f + __expf(-a0));
        out[o + 1] = 1.f / (1.f + __expf(-a1));
        out[o + 2] = 1.f / (1.f + __expf(-a2));
    }
}

extern "C" void kernel_launch(void* const* d_in, const int* in_sizes, int n_in,
                              void* d_out, int out_size, void* d_ws, size_t ws_size,
                              hipStream_t stream) {
    const float* x  = (const float*)d_in[0];
    const float* W0 = (const float*)d_in[1];
    WPtrs wp;
    for (int i = 0; i < 6; ++i) wp.w[i] = (const float*)d_in[2 + i];
    const float* W7 = (const float*)d_in[8];
    float* out = (float*)d_out;
    unsigned short* Wp = (unsigned short*)d_ws;   // 786,432 B

    pack_w_kernel<<<192, 256, 0, stream>>>(wp, Wp);
    mlp_fused_kernel<<<NBLK, 256, 0, stream>>>(x, W0, W7, Wp, out);
}